// Round 13
// baseline (766.989 us; speedup 1.0000x reference)
//
#include <hip/hip_runtime.h>
#include <hip/hip_bf16.h>

typedef unsigned short u16;
typedef unsigned int u32;
typedef __attribute__((ext_vector_type(8))) short short8;
typedef __attribute__((ext_vector_type(4))) float floatx4;

#define N_PTS 16384
#define N_GRID 4096
#define GPTS 512
#define HD 128
#define DEG 16
#define QB 4
#define EB 64

__device__ __forceinline__ float silu_f(float x) { return x / (1.0f + __expf(-x)); }
__device__ __forceinline__ short f2bf(float x) { return (short)__bfloat16_as_ushort(__float2bfloat16(x)); }

__global__ void k_fillf(float* out, float v, int n) {
    int i = blockIdx.x * blockDim.x + threadIdx.x;
    if (i < n) out[i] = v;
}

__global__ void k_init(const float* __restrict__ qp, const float* __restrict__ codes,
                       float* __restrict__ x_q, float* __restrict__ h_g, float* __restrict__ h_q) {
    int stride = gridDim.x * blockDim.x;
    int i0 = blockIdx.x * blockDim.x + threadIdx.x;
    for (int i = i0; i < N_PTS * 3; i += stride) x_q[i] = qp[i];
    for (int i = i0; i < N_GRID * HD; i += stride) h_g[i] = codes[i];
    for (int i = i0; i < N_PTS * HD; i += stride) h_q[i] = 0.0f;
}

// transpose We2 -> bf16 wsT[layer][f*128+k]
__global__ void k_prep(const float* __restrict__ eW2, short* __restrict__ wsT) {
    int idx = blockIdx.x * blockDim.x + threadIdx.x;
    if (idx >= 4 * HD * HD) return;
    int l = idx >> 14, rem = idx & 16383, f = rem >> 7, k = rem & 127;
    wsT[idx] = f2bf(eW2[l * 16384 + k * HD + f]);
}

// ---------------- grid nodes, tile-GEMM style: 32 nodes/block ----------------
__global__ __launch_bounds__(256) void k_gridT(
    const float* __restrict__ hg, float* __restrict__ Ag,
    const float* __restrict__ W1top, const float* __restrict__ b1,
    const float* __restrict__ Wn1top, const float* __restrict__ bn1,
    const float* __restrict__ Wn2, const float* __restrict__ bn2,
    int updateH, float* __restrict__ hg_out) {
    __shared__ float hgT[HD * 36];   // [j][node]
    __shared__ float stT[HD * 36];   // [k][node]
    int tid = threadIdx.x;
    int n0 = blockIdx.x * 32;
    {
        int q = tid & 31, j0 = (tid >> 5) * 16;
#pragma unroll
        for (int s = 0; s < 4; s++) {
            float4 v = *(const float4*)&hg[(n0 + q) * HD + j0 + s * 4];
            hgT[(j0 + s * 4 + 0) * 36 + q] = v.x;
            hgT[(j0 + s * 4 + 1) * 36 + q] = v.y;
            hgT[(j0 + s * 4 + 2) * 36 + q] = v.z;
            hgT[(j0 + s * 4 + 3) * 36 + q] = v.w;
        }
    }
    __syncthreads();
    int f0 = (tid & 31) * 4;
    int ng = (tid >> 5) * 4;
    float4 acc[4];
    {
        float4 bv = *(const float4*)&b1[f0];
#pragma unroll
        for (int qq = 0; qq < 4; qq++) acc[qq] = bv;
#pragma unroll 4
        for (int j = 0; j < HD; j++) {
            float4 a = *(const float4*)&hgT[j * 36 + ng];
            float4 w = *(const float4*)&W1top[j * HD + f0];
            acc[0].x += a.x * w.x; acc[0].y += a.x * w.y; acc[0].z += a.x * w.z; acc[0].w += a.x * w.w;
            acc[1].x += a.y * w.x; acc[1].y += a.y * w.y; acc[1].z += a.y * w.z; acc[1].w += a.y * w.w;
            acc[2].x += a.z * w.x; acc[2].y += a.z * w.y; acc[2].z += a.z * w.z; acc[2].w += a.z * w.w;
            acc[3].x += a.w * w.x; acc[3].y += a.w * w.y; acc[3].z += a.w * w.z; acc[3].w += a.w * w.w;
        }
#pragma unroll
        for (int qq = 0; qq < 4; qq++)
            *(float4*)&Ag[(n0 + ng + qq) * HD + f0] = acc[qq];
    }
    if (updateH) {
        float4 bv = *(const float4*)&bn1[f0];
#pragma unroll
        for (int qq = 0; qq < 4; qq++) acc[qq] = bv;
#pragma unroll 4
        for (int j = 0; j < HD; j++) {
            float4 a = *(const float4*)&hgT[j * 36 + ng];
            float4 w = *(const float4*)&Wn1top[j * HD + f0];
            acc[0].x += a.x * w.x; acc[0].y += a.x * w.y; acc[0].z += a.x * w.z; acc[0].w += a.x * w.w;
            acc[1].x += a.y * w.x; acc[1].y += a.y * w.y; acc[1].z += a.y * w.z; acc[1].w += a.y * w.w;
            acc[2].x += a.z * w.x; acc[2].y += a.z * w.y; acc[2].z += a.z * w.z; acc[2].w += a.z * w.w;
            acc[3].x += a.w * w.x; acc[3].y += a.w * w.y; acc[3].z += a.w * w.z; acc[3].w += a.w * w.w;
        }
#pragma unroll
        for (int qq = 0; qq < 4; qq++) {
            stT[(f0 + 0) * 36 + ng + qq] = silu_f(acc[qq].x);
            stT[(f0 + 1) * 36 + ng + qq] = silu_f(acc[qq].y);
            stT[(f0 + 2) * 36 + ng + qq] = silu_f(acc[qq].z);
            stT[(f0 + 3) * 36 + ng + qq] = silu_f(acc[qq].w);
        }
        __syncthreads();
        bv = *(const float4*)&bn2[f0];
#pragma unroll
        for (int qq = 0; qq < 4; qq++) acc[qq] = bv;
#pragma unroll 4
        for (int j = 0; j < HD; j++) {
            float4 a = *(const float4*)&stT[j * 36 + ng];
            float4 w = *(const float4*)&Wn2[j * HD + f0];
            acc[0].x += a.x * w.x; acc[0].y += a.x * w.y; acc[0].z += a.x * w.z; acc[0].w += a.x * w.w;
            acc[1].x += a.y * w.x; acc[1].y += a.y * w.y; acc[1].z += a.y * w.z; acc[1].w += a.y * w.w;
            acc[2].x += a.z * w.x; acc[2].y += a.z * w.y; acc[2].z += a.z * w.z; acc[2].w += a.z * w.w;
            acc[3].x += a.w * w.x; acc[3].y += a.w * w.y; acc[3].z += a.w * w.z; acc[3].w += a.w * w.w;
        }
#pragma unroll
        for (int qq = 0; qq < 4; qq++) {
            float4 h;
            h.x = hgT[(f0 + 0) * 36 + ng + qq] + acc[qq].x;
            h.y = hgT[(f0 + 1) * 36 + ng + qq] + acc[qq].y;
            h.z = hgT[(f0 + 2) * 36 + ng + qq] + acc[qq].z;
            h.w = hgT[(f0 + 3) * 36 + ng + qq] + acc[qq].w;
            *(float4*)&hg_out[(n0 + ng + qq) * HD + f0] = h;
        }
    }
}

// ---------------- Bq = h_q @ We1_mid : fp32 tile GEMM, 32 queries/block ----------------
__global__ __launch_bounds__(256) void k_bq(
    const float* __restrict__ hq, const float* __restrict__ W1mid, float* __restrict__ Bq) {
    __shared__ float shT[HD * 36];
    int tid = threadIdx.x;
    int q0 = blockIdx.x * 32;
    {
        int q = tid & 31, j0 = (tid >> 5) * 16;
#pragma unroll
        for (int s = 0; s < 4; s++) {
            float4 v = *(const float4*)&hq[(q0 + q) * HD + j0 + s * 4];
            shT[(j0 + s * 4 + 0) * 36 + q] = v.x;
            shT[(j0 + s * 4 + 1) * 36 + q] = v.y;
            shT[(j0 + s * 4 + 2) * 36 + q] = v.z;
            shT[(j0 + s * 4 + 3) * 36 + q] = v.w;
        }
    }
    __syncthreads();
    int f0 = (tid & 31) * 4;
    int qg = (tid >> 5) * 4;
    float4 acc[4] = {};
#pragma unroll 4
    for (int j = 0; j < HD; j++) {
        float4 a = *(const float4*)&shT[j * 36 + qg];
        float4 w = *(const float4*)&W1mid[j * HD + f0];
        acc[0].x += a.x * w.x; acc[0].y += a.x * w.y; acc[0].z += a.x * w.z; acc[0].w += a.x * w.w;
        acc[1].x += a.y * w.x; acc[1].y += a.y * w.y; acc[1].z += a.y * w.z; acc[1].w += a.y * w.w;
        acc[2].x += a.z * w.x; acc[2].y += a.z * w.y; acc[2].z += a.z * w.z; acc[2].w += a.z * w.w;
        acc[3].x += a.w * w.x; acc[3].y += a.w * w.y; acc[3].z += a.w * w.z; acc[3].w += a.w * w.w;
    }
#pragma unroll
    for (int qq = 0; qq < 4; qq++)
        *(float4*)&Bq[(q0 + qg + qq) * HD + f0] = acc[qq];
}

// ---------------- node MLP: h += silu([h,mg]@Wn1+bn1)@Wn2+bn2 : 32 queries/block ----------------
__global__ __launch_bounds__(256) void k_node(
    float* __restrict__ hq, const float* __restrict__ mg,
    const float* __restrict__ Wn1, const float* __restrict__ bn1,
    const float* __restrict__ Wn2, const float* __restrict__ bn2) {
    __shared__ float aT[256 * 36];
    __shared__ float stT[HD * 36];
    int tid = threadIdx.x;
    int q0 = blockIdx.x * 32;
    {
        int q = tid & 31, j0 = (tid >> 5) * 16;
#pragma unroll
        for (int s = 0; s < 4; s++) {
            float4 v = *(const float4*)&hq[(q0 + q) * HD + j0 + s * 4];
            aT[(j0 + s * 4 + 0) * 36 + q] = v.x;
            aT[(j0 + s * 4 + 1) * 36 + q] = v.y;
            aT[(j0 + s * 4 + 2) * 36 + q] = v.z;
            aT[(j0 + s * 4 + 3) * 36 + q] = v.w;
            float4 m = *(const float4*)&mg[(q0 + q) * HD + j0 + s * 4];
            aT[(128 + j0 + s * 4 + 0) * 36 + q] = m.x;
            aT[(128 + j0 + s * 4 + 1) * 36 + q] = m.y;
            aT[(128 + j0 + s * 4 + 2) * 36 + q] = m.z;
            aT[(128 + j0 + s * 4 + 3) * 36 + q] = m.w;
        }
    }
    __syncthreads();
    int f0 = (tid & 31) * 4;
    int qg = (tid >> 5) * 4;
    float4 bn1v = *(const float4*)&bn1[f0];
    float4 acc[4];
#pragma unroll
    for (int qq = 0; qq < 4; qq++) acc[qq] = bn1v;
#pragma unroll 4
    for (int j = 0; j < 256; j++) {
        float4 a = *(const float4*)&aT[j * 36 + qg];
        float4 w = *(const float4*)&Wn1[j * HD + f0];
        acc[0].x += a.x * w.x; acc[0].y += a.x * w.y; acc[0].z += a.x * w.z; acc[0].w += a.x * w.w;
        acc[1].x += a.y * w.x; acc[1].y += a.y * w.y; acc[1].z += a.y * w.z; acc[1].w += a.y * w.w;
        acc[2].x += a.z * w.x; acc[2].y += a.z * w.y; acc[2].z += a.z * w.z; acc[2].w += a.z * w.w;
        acc[3].x += a.w * w.x; acc[3].y += a.w * w.y; acc[3].z += a.w * w.z; acc[3].w += a.w * w.w;
    }
#pragma unroll
    for (int qq = 0; qq < 4; qq++) {
        stT[(f0 + 0) * 36 + qg + qq] = silu_f(acc[qq].x);
        stT[(f0 + 1) * 36 + qg + qq] = silu_f(acc[qq].y);
        stT[(f0 + 2) * 36 + qg + qq] = silu_f(acc[qq].z);
        stT[(f0 + 3) * 36 + qg + qq] = silu_f(acc[qq].w);
    }
    __syncthreads();
    float4 bn2v = *(const float4*)&bn2[f0];
#pragma unroll
    for (int qq = 0; qq < 4; qq++) acc[qq] = bn2v;
#pragma unroll 4
    for (int j = 0; j < HD; j++) {
        float4 a = *(const float4*)&stT[j * 36 + qg];
        float4 w = *(const float4*)&Wn2[j * HD + f0];
        acc[0].x += a.x * w.x; acc[0].y += a.x * w.y; acc[0].z += a.x * w.z; acc[0].w += a.x * w.w;
        acc[1].x += a.y * w.x; acc[1].y += a.y * w.y; acc[1].z += a.y * w.z; acc[1].w += a.y * w.w;
        acc[2].x += a.z * w.x; acc[2].y += a.z * w.y; acc[2].z += a.z * w.z; acc[2].w += a.z * w.w;
        acc[3].x += a.w * w.x; acc[3].y += a.w * w.y; acc[3].z += a.w * w.z; acc[3].w += a.w * w.w;
    }
#pragma unroll
    for (int qq = 0; qq < 4; qq++) {
        float4 h = *(const float4*)&hq[(q0 + qg + qq) * HD + f0];
        h.x += acc[qq].x; h.y += acc[qq].y; h.z += acc[qq].z; h.w += acc[qq].w;
        *(float4*)&hq[(q0 + qg + qq) * HD + f0] = h;
    }
}

// ---------------- lean MFMA edge kernel: 4 queries (64 edges) per block, 1 query/wave ----------------
template <int OUTT, bool FIN>
__global__ __launch_bounds__(256, 4) void k_edge(
    const float* __restrict__ Ag, const float* __restrict__ Bq, float* __restrict__ x_q,
    const float* __restrict__ wdrow, const short* __restrict__ wsT,
    const float* __restrict__ b2v, const float* __restrict__ Wc, const float* __restrict__ cbp,
    const int* __restrict__ erow, const float* __restrict__ gridp,
    const float* __restrict__ qp, float* __restrict__ out, float* __restrict__ maggr) {
    __shared__ float sdist[EB];
    __shared__ float scm[EB];
    __shared__ float sdir[3 * EB];
    __shared__ int   sgi[EB];
    __shared__ float scoef[EB * OUTT];
    __shared__ float xs[QB * 3];

    int tid = threadIdx.x;
    int q0 = blockIdx.x * QB;
    int wid = tid >> 6, lane = tid & 63, quad = lane >> 4, c = lane & 15;

    if (tid < QB * 3) xs[tid] = x_q[q0 * 3 + tid];
    __syncthreads();
    if (tid < EB) {
        int e = tid, q = e >> 4;
        int gi = erow[q0 * DEG + e] - N_PTS;
        sgi[e] = gi;
        int gl = gi & (GPTS - 1);
        float r0 = gridp[gl * 3 + 0] - xs[q * 3 + 0];
        float r1 = gridp[gl * 3 + 1] - xs[q * 3 + 1];
        float r2 = gridp[gl * 3 + 2] - xs[q * 3 + 2];
        float dist = sqrtf(r0 * r0 + r1 * r1 + r2 * r2);
        float inv = 1.0f / (dist + 1e-8f);
        sdist[e] = dist;
        sdir[0 * EB + e] = r0 * inv;
        sdir[1 * EB + e] = r1 * inv;
        sdir[2 * EB + e] = r2 * inv;
        float cw = 0.5f * (__cosf(dist * 0.31415926535897931f) + 1.0f);
        scm[e] = (dist <= 10.0f) ? cw : 0.0f;
    }
    __syncthreads();

    int q = wid;                 // one query per wave
    int e = q * 16 + c;
    int gi = sgi[e];
    float dist = sdist[e];

    floatx4 acc[8];
#pragma unroll
    for (int n = 0; n < 8; n++) acc[n] = (floatx4)0.f;

#pragma unroll
    for (int ch = 0; ch < 4; ch++) {
        int kb = ch * 32 + quad * 8;
        float4 wd0 = *(const float4*)(wdrow + kb);
        float4 wd1 = *(const float4*)(wdrow + kb + 4);
        const float4* ap = (const float4*)(Ag + gi * HD + kb);
        float4 a0 = ap[0], a1 = ap[1];
        const float4* bp4 = (const float4*)(Bq + (q0 + q) * HD + kb);
        float4 b0 = bp4[0], b1 = bp4[1];
        short8 afr;
        afr[0] = f2bf(silu_f(a0.x + b0.x + dist * wd0.x));
        afr[1] = f2bf(silu_f(a0.y + b0.y + dist * wd0.y));
        afr[2] = f2bf(silu_f(a0.z + b0.z + dist * wd0.z));
        afr[3] = f2bf(silu_f(a0.w + b0.w + dist * wd0.w));
        afr[4] = f2bf(silu_f(a1.x + b1.x + dist * wd1.x));
        afr[5] = f2bf(silu_f(a1.y + b1.y + dist * wd1.y));
        afr[6] = f2bf(silu_f(a1.z + b1.z + dist * wd1.z));
        afr[7] = f2bf(silu_f(a1.w + b1.w + dist * wd1.w));
#pragma unroll
        for (int n = 0; n < 8; n++) {
            short8 bfr = *(const short8*)(wsT + (n * 16 + c) * HD + kb);
            acc[n] = __builtin_amdgcn_mfma_f32_16x16x32_bf16(afr, bfr, acc[n], 0, 0, 0);
        }
    }

    {
        int ebase = q * 16;
        float cmr[4];
#pragma unroll
        for (int r = 0; r < 4; r++) cmr[r] = scm[ebase + quad * 4 + r];
        float apc[4][OUTT];
#pragma unroll
        for (int r = 0; r < 4; r++)
#pragma unroll
            for (int t = 0; t < OUTT; t++) apc[r][t] = 0.f;
#pragma unroll
        for (int n = 0; n < 8; n++) {
            int f = n * 16 + c;
            float be2v = b2v[f];
            float wcv[OUTT];
            if (FIN) {
#pragma unroll
                for (int t = 0; t < OUTT; t++) wcv[t] = Wc[f * 5 + t];
            } else {
                wcv[0] = Wc[f];
            }
            float cs = 0.f;
#pragma unroll
            for (int r = 0; r < 4; r++) {
                float v = silu_f(acc[n][r] + be2v) * cmr[r];
                cs += v;
#pragma unroll
                for (int t = 0; t < OUTT; t++) apc[r][t] += v * wcv[t];
            }
            cs += __shfl_xor(cs, 16, 64);
            cs += __shfl_xor(cs, 32, 64);
            if (!FIN && lane < 16) maggr[(q0 + q) * HD + f] = cs * 0.0625f;
        }
#pragma unroll
        for (int t = 0; t < OUTT; t++) {
#pragma unroll
            for (int r = 0; r < 4; r++) {
                float v = apc[r][t];
                v += __shfl_xor(v, 1, 64);
                v += __shfl_xor(v, 2, 64);
                v += __shfl_xor(v, 4, 64);
                v += __shfl_xor(v, 8, 64);
                if (c == 0) scoef[(ebase + quad * 4 + r) * OUTT + t] = v;
            }
        }
    }
    __syncthreads();

    if (tid < QB * 3 * OUTT) {
        int qq = tid / (3 * OUTT), rem = tid % (3 * OUTT), t = rem / 3, c2 = rem % 3;
        float cbv = cbp[t];
        float s = 0.f;
#pragma unroll 4
        for (int r = 0; r < 16; r++) {
            int ee = qq * 16 + r;
            s += (scoef[ee * OUTT + t] + cbv) * sdir[c2 * EB + ee];
        }
        float dd = s * 0.0625f;
        if (FIN) out[(q0 + qq) * 15 + t * 3 + c2] = xs[qq * 3 + c2] + dd - qp[(q0 + qq) * 3 + c2];
        else x_q[(q0 + qq) * 3 + c2] = xs[qq * 3 + c2] + dd;
    }
}

extern "C" void kernel_launch(void* const* d_in, const int* in_sizes, int n_in,
                              void* d_out, int out_size, void* d_ws, size_t ws_size,
                              hipStream_t stream) {
    float* out = (float*)d_out;
    int fill_blocks = (out_size + 255) / 256;

    static const int exp_sz[16] = { 49152, 524288, 1536, 131584, 512, 65536, 512, 384,
                                    3, 640, 5, 131072, 512, 65536, 512, 524288 };
    bool ok = (n_in == 16);
    for (int i = 0; ok && i < 16; i++) if (in_sizes[i] != exp_sz[i]) ok = false;
    if (!ok || ws_size < (size_t)40 * 1024 * 1024) {
        k_fillf<<<fill_blocks, 256, 0, stream>>>(out, 777.0f, out_size);
        return;
    }

    const float* qp    = (const float*)d_in[0];
    const float* codes = (const float*)d_in[1];
    const float* gridp = (const float*)d_in[2];
    const float* eW1   = (const float*)d_in[3];
    const float* eb1   = (const float*)d_in[4];
    const float* eW2   = (const float*)d_in[5];
    const float* eb2   = (const float*)d_in[6];
    const float* cW    = (const float*)d_in[7];
    const float* cb    = (const float*)d_in[8];
    const float* fcW   = (const float*)d_in[9];
    const float* fcb   = (const float*)d_in[10];
    const float* nW1   = (const float*)d_in[11];
    const float* nb1   = (const float*)d_in[12];
    const float* nW2   = (const float*)d_in[13];
    const float* nb2   = (const float*)d_in[14];
    const int*   erow  = (const int*)d_in[15];

    float* ws = (float*)d_ws;
    float* x_q  = ws;  ws += N_PTS * 3;
    float* h_q  = ws;  ws += N_PTS * HD;
    float* hg_a = ws;  ws += N_GRID * HD;
    float* hg_b = ws;  ws += N_GRID * HD;
    float* A_g  = ws;  ws += N_GRID * HD;
    float* Bqb  = ws;  ws += N_PTS * HD;
    float* mgb  = ws;  ws += N_PTS * HD;
    short* wsT  = (short*)ws;   // 4 layers x 16384 bf16

    k_init<<<2048, 256, 0, stream>>>(qp, codes, x_q, hg_a, h_q);
    k_prep<<<(4 * HD * HD + 255) / 256, 256, 0, stream>>>(eW2, wsT);

    float* hg_cur = hg_a;
    float* hg_next = hg_b;
    for (int i = 0; i < 4; i++) {
        int fin = (i == 3);
        const float* W1l = eW1 + i * 257 * 128;
        k_gridT<<<N_GRID / 32, 256, 0, stream>>>(hg_cur, A_g, W1l, eb1 + i * 128,
                                                 nW1 + i * 256 * 128, nb1 + i * 128,
                                                 nW2 + i * 16384, nb2 + i * 128,
                                                 fin ? 0 : 1, hg_next);
        k_bq<<<N_PTS / 32, 256, 0, stream>>>(h_q, W1l + 128 * 128, Bqb);
        if (!fin) {
            k_edge<1, false><<<N_PTS / QB, 256, 0, stream>>>(A_g, Bqb, x_q,
                W1l + 256 * 128, wsT + i * 16384, eb2 + i * 128,
                cW + i * 128, cb + i, erow, gridp, qp, out, mgb);
            k_node<<<N_PTS / 32, 256, 0, stream>>>(h_q, mgb, nW1 + i * 256 * 128,
                nb1 + i * 128, nW2 + i * 16384, nb2 + i * 128);
        } else {
            k_edge<5, true><<<N_PTS / QB, 256, 0, stream>>>(A_g, Bqb, x_q,
                W1l + 256 * 128, wsT + i * 16384, eb2 + i * 128,
                fcW, fcb, erow, gridp, qp, out, mgb);
        }
        float* tmp = hg_cur; hg_cur = hg_next; hg_next = tmp;
    }
}

// Round 14
// 633.640 us; speedup vs baseline: 1.2104x; 1.2104x over previous
//
#include <hip/hip_runtime.h>
#include <hip/hip_bf16.h>

typedef unsigned short u16;
typedef unsigned int u32;
typedef __attribute__((ext_vector_type(8))) short short8;
typedef __attribute__((ext_vector_type(4))) float floatx4;

#define N_PTS 16384
#define N_GRID 4096
#define GPTS 512
#define HD 128
#define DEG 16
#define QB 8
#define EB 128

__device__ __forceinline__ float silu_f(float x) { return x / (1.0f + __expf(-x)); }
__device__ __forceinline__ short f2bf(float x) { return (short)__bfloat16_as_ushort(__float2bfloat16(x)); }

__global__ void k_fillf(float* out, float v, int n) {
    int i = blockIdx.x * blockDim.x + threadIdx.x;
    if (i < n) out[i] = v;
}

__global__ void k_init(const float* __restrict__ qp, const float* __restrict__ codes,
                       float* __restrict__ x_q, float* __restrict__ h_g, float* __restrict__ h_q) {
    int stride = gridDim.x * blockDim.x;
    int i0 = blockIdx.x * blockDim.x + threadIdx.x;
    for (int i = i0; i < N_PTS * 3; i += stride) x_q[i] = qp[i];
    for (int i = i0; i < N_GRID * HD; i += stride) h_g[i] = codes[i];
    for (int i = i0; i < N_PTS * HD; i += stride) h_q[i] = 0.0f;
}

// transpose We2 -> bf16 wsT[layer][f*128+k]
__global__ void k_prep(const float* __restrict__ eW2, short* __restrict__ wsT) {
    int idx = blockIdx.x * blockDim.x + threadIdx.x;
    if (idx >= 4 * HD * HD) return;
    int l = idx >> 14, rem = idx & 16383, f = rem >> 7, k = rem & 127;
    wsT[idx] = f2bf(eW2[l * 16384 + k * HD + f]);
}

// ---------------- merged: grid-node GEMMs (blocks 0..127) + Bq GEMM (blocks 128..639) ----------------
__global__ __launch_bounds__(256) void k_gb(
    const float* __restrict__ hg, float* __restrict__ Ag,
    const float* __restrict__ W1top, const float* __restrict__ b1,
    const float* __restrict__ Wn1top, const float* __restrict__ bn1,
    const float* __restrict__ Wn2, const float* __restrict__ bn2,
    int updateH, float* __restrict__ hg_out,
    const float* __restrict__ hq, const float* __restrict__ W1mid, float* __restrict__ Bq) {
    __shared__ float T1[HD * 36];
    __shared__ float T2[HD * 36];
    int tid = threadIdx.x;
    int blk = blockIdx.x;
    int f0 = (tid & 31) * 4;
    int ng = (tid >> 5) * 4;
    if (blk < N_GRID / 32) {
        int n0 = blk * 32;
        {
            int q = tid & 31, j0 = (tid >> 5) * 16;
#pragma unroll
            for (int s = 0; s < 4; s++) {
                float4 v = *(const float4*)&hg[(n0 + q) * HD + j0 + s * 4];
                T1[(j0 + s * 4 + 0) * 36 + q] = v.x;
                T1[(j0 + s * 4 + 1) * 36 + q] = v.y;
                T1[(j0 + s * 4 + 2) * 36 + q] = v.z;
                T1[(j0 + s * 4 + 3) * 36 + q] = v.w;
            }
        }
        __syncthreads();
        float4 acc[4];
        {
            float4 bv = *(const float4*)&b1[f0];
#pragma unroll
            for (int qq = 0; qq < 4; qq++) acc[qq] = bv;
#pragma unroll 4
            for (int j = 0; j < HD; j++) {
                float4 a = *(const float4*)&T1[j * 36 + ng];
                float4 w = *(const float4*)&W1top[j * HD + f0];
                acc[0].x += a.x * w.x; acc[0].y += a.x * w.y; acc[0].z += a.x * w.z; acc[0].w += a.x * w.w;
                acc[1].x += a.y * w.x; acc[1].y += a.y * w.y; acc[1].z += a.y * w.z; acc[1].w += a.y * w.w;
                acc[2].x += a.z * w.x; acc[2].y += a.z * w.y; acc[2].z += a.z * w.z; acc[2].w += a.z * w.w;
                acc[3].x += a.w * w.x; acc[3].y += a.w * w.y; acc[3].z += a.w * w.z; acc[3].w += a.w * w.w;
            }
#pragma unroll
            for (int qq = 0; qq < 4; qq++)
                *(float4*)&Ag[(n0 + ng + qq) * HD + f0] = acc[qq];
        }
        if (updateH) {
            float4 bv = *(const float4*)&bn1[f0];
#pragma unroll
            for (int qq = 0; qq < 4; qq++) acc[qq] = bv;
#pragma unroll 4
            for (int j = 0; j < HD; j++) {
                float4 a = *(const float4*)&T1[j * 36 + ng];
                float4 w = *(const float4*)&Wn1top[j * HD + f0];
                acc[0].x += a.x * w.x; acc[0].y += a.x * w.y; acc[0].z += a.x * w.z; acc[0].w += a.x * w.w;
                acc[1].x += a.y * w.x; acc[1].y += a.y * w.y; acc[1].z += a.y * w.z; acc[1].w += a.y * w.w;
                acc[2].x += a.z * w.x; acc[2].y += a.z * w.y; acc[2].z += a.z * w.z; acc[2].w += a.z * w.w;
                acc[3].x += a.w * w.x; acc[3].y += a.w * w.y; acc[3].z += a.w * w.z; acc[3].w += a.w * w.w;
            }
#pragma unroll
            for (int qq = 0; qq < 4; qq++) {
                T2[(f0 + 0) * 36 + ng + qq] = silu_f(acc[qq].x);
                T2[(f0 + 1) * 36 + ng + qq] = silu_f(acc[qq].y);
                T2[(f0 + 2) * 36 + ng + qq] = silu_f(acc[qq].z);
                T2[(f0 + 3) * 36 + ng + qq] = silu_f(acc[qq].w);
            }
            __syncthreads();
            bv = *(const float4*)&bn2[f0];
#pragma unroll
            for (int qq = 0; qq < 4; qq++) acc[qq] = bv;
#pragma unroll 4
            for (int j = 0; j < HD; j++) {
                float4 a = *(const float4*)&T2[j * 36 + ng];
                float4 w = *(const float4*)&Wn2[j * HD + f0];
                acc[0].x += a.x * w.x; acc[0].y += a.x * w.y; acc[0].z += a.x * w.z; acc[0].w += a.x * w.w;
                acc[1].x += a.y * w.x; acc[1].y += a.y * w.y; acc[1].z += a.y * w.z; acc[1].w += a.y * w.w;
                acc[2].x += a.z * w.x; acc[2].y += a.z * w.y; acc[2].z += a.z * w.z; acc[2].w += a.z * w.w;
                acc[3].x += a.w * w.x; acc[3].y += a.w * w.y; acc[3].z += a.w * w.z; acc[3].w += a.w * w.w;
            }
#pragma unroll
            for (int qq = 0; qq < 4; qq++) {
                float4 h;
                h.x = T1[(f0 + 0) * 36 + ng + qq] + acc[qq].x;
                h.y = T1[(f0 + 1) * 36 + ng + qq] + acc[qq].y;
                h.z = T1[(f0 + 2) * 36 + ng + qq] + acc[qq].z;
                h.w = T1[(f0 + 3) * 36 + ng + qq] + acc[qq].w;
                *(float4*)&hg_out[(n0 + ng + qq) * HD + f0] = h;
            }
        }
    } else {
        int q0 = (blk - N_GRID / 32) * 32;
        {
            int q = tid & 31, j0 = (tid >> 5) * 16;
#pragma unroll
            for (int s = 0; s < 4; s++) {
                float4 v = *(const float4*)&hq[(q0 + q) * HD + j0 + s * 4];
                T1[(j0 + s * 4 + 0) * 36 + q] = v.x;
                T1[(j0 + s * 4 + 1) * 36 + q] = v.y;
                T1[(j0 + s * 4 + 2) * 36 + q] = v.z;
                T1[(j0 + s * 4 + 3) * 36 + q] = v.w;
            }
        }
        __syncthreads();
        float4 acc[4] = {};
#pragma unroll 4
        for (int j = 0; j < HD; j++) {
            float4 a = *(const float4*)&T1[j * 36 + ng];
            float4 w = *(const float4*)&W1mid[j * HD + f0];
            acc[0].x += a.x * w.x; acc[0].y += a.x * w.y; acc[0].z += a.x * w.z; acc[0].w += a.x * w.w;
            acc[1].x += a.y * w.x; acc[1].y += a.y * w.y; acc[1].z += a.y * w.z; acc[1].w += a.y * w.w;
            acc[2].x += a.z * w.x; acc[2].y += a.z * w.y; acc[2].z += a.z * w.z; acc[2].w += a.z * w.w;
            acc[3].x += a.w * w.x; acc[3].y += a.w * w.y; acc[3].z += a.w * w.z; acc[3].w += a.w * w.w;
        }
#pragma unroll
        for (int qq = 0; qq < 4; qq++)
            *(float4*)&Bq[(q0 + ng + qq) * HD + f0] = acc[qq];
    }
}

// ---------------- node MLP: h += silu([h,mg]@Wn1+bn1)@Wn2+bn2 : 32 queries/block ----------------
__global__ __launch_bounds__(256) void k_node(
    float* __restrict__ hq, const float* __restrict__ mg,
    const float* __restrict__ Wn1, const float* __restrict__ bn1,
    const float* __restrict__ Wn2, const float* __restrict__ bn2) {
    __shared__ float aT[256 * 36];
    __shared__ float stT[HD * 36];
    int tid = threadIdx.x;
    int q0 = blockIdx.x * 32;
    {
        int q = tid & 31, j0 = (tid >> 5) * 16;
#pragma unroll
        for (int s = 0; s < 4; s++) {
            float4 v = *(const float4*)&hq[(q0 + q) * HD + j0 + s * 4];
            aT[(j0 + s * 4 + 0) * 36 + q] = v.x;
            aT[(j0 + s * 4 + 1) * 36 + q] = v.y;
            aT[(j0 + s * 4 + 2) * 36 + q] = v.z;
            aT[(j0 + s * 4 + 3) * 36 + q] = v.w;
            float4 m = *(const float4*)&mg[(q0 + q) * HD + j0 + s * 4];
            aT[(128 + j0 + s * 4 + 0) * 36 + q] = m.x;
            aT[(128 + j0 + s * 4 + 1) * 36 + q] = m.y;
            aT[(128 + j0 + s * 4 + 2) * 36 + q] = m.z;
            aT[(128 + j0 + s * 4 + 3) * 36 + q] = m.w;
        }
    }
    __syncthreads();
    int f0 = (tid & 31) * 4;
    int qg = (tid >> 5) * 4;
    float4 bn1v = *(const float4*)&bn1[f0];
    float4 acc[4];
#pragma unroll
    for (int qq = 0; qq < 4; qq++) acc[qq] = bn1v;
#pragma unroll 4
    for (int j = 0; j < 256; j++) {
        float4 a = *(const float4*)&aT[j * 36 + qg];
        float4 w = *(const float4*)&Wn1[j * HD + f0];
        acc[0].x += a.x * w.x; acc[0].y += a.x * w.y; acc[0].z += a.x * w.z; acc[0].w += a.x * w.w;
        acc[1].x += a.y * w.x; acc[1].y += a.y * w.y; acc[1].z += a.y * w.z; acc[1].w += a.y * w.w;
        acc[2].x += a.z * w.x; acc[2].y += a.z * w.y; acc[2].z += a.z * w.z; acc[2].w += a.z * w.w;
        acc[3].x += a.w * w.x; acc[3].y += a.w * w.y; acc[3].z += a.w * w.z; acc[3].w += a.w * w.w;
    }
#pragma unroll
    for (int qq = 0; qq < 4; qq++) {
        stT[(f0 + 0) * 36 + qg + qq] = silu_f(acc[qq].x);
        stT[(f0 + 1) * 36 + qg + qq] = silu_f(acc[qq].y);
        stT[(f0 + 2) * 36 + qg + qq] = silu_f(acc[qq].z);
        stT[(f0 + 3) * 36 + qg + qq] = silu_f(acc[qq].w);
    }
    __syncthreads();
    float4 bn2v = *(const float4*)&bn2[f0];
#pragma unroll
    for (int qq = 0; qq < 4; qq++) acc[qq] = bn2v;
#pragma unroll 4
    for (int j = 0; j < HD; j++) {
        float4 a = *(const float4*)&stT[j * 36 + qg];
        float4 w = *(const float4*)&Wn2[j * HD + f0];
        acc[0].x += a.x * w.x; acc[0].y += a.x * w.y; acc[0].z += a.x * w.z; acc[0].w += a.x * w.w;
        acc[1].x += a.y * w.x; acc[1].y += a.y * w.y; acc[1].z += a.y * w.z; acc[1].w += a.y * w.w;
        acc[2].x += a.z * w.x; acc[2].y += a.z * w.y; acc[2].z += a.z * w.z; acc[2].w += a.z * w.w;
        acc[3].x += a.w * w.x; acc[3].y += a.w * w.y; acc[3].z += a.w * w.z; acc[3].w += a.w * w.w;
    }
#pragma unroll
    for (int qq = 0; qq < 4; qq++) {
        float4 h = *(const float4*)&hq[(q0 + qg + qq) * HD + f0];
        h.x += acc[qq].x; h.y += acc[qq].y; h.z += acc[qq].z; h.w += acc[qq].w;
        *(float4*)&hq[(q0 + qg + qq) * HD + f0] = h;
    }
}

// ---------------- lean MFMA edge kernel: 8 queries (128 edges)/block, 2 q/wave, Ag prefetch ----------------
template <int OUTT, bool FIN>
__global__ __launch_bounds__(256, 3) void k_edge(
    const float* __restrict__ Ag, const float* __restrict__ Bq, float* __restrict__ x_q,
    const float* __restrict__ wdrow, const short* __restrict__ wsT,
    const float* __restrict__ b2v, const float* __restrict__ Wc, const float* __restrict__ cbp,
    const int* __restrict__ erow, const float* __restrict__ gridp,
    const float* __restrict__ qp, float* __restrict__ out, float* __restrict__ maggr) {
    __shared__ float sdist[EB];
    __shared__ float scm[EB];
    __shared__ float sdir[3 * EB];
    __shared__ int   sgi[EB];
    __shared__ float scoef[EB * OUTT];
    __shared__ float xs[QB * 3];

    int tid = threadIdx.x;
    int q0 = blockIdx.x * QB;
    int wid = tid >> 6, lane = tid & 63, quad = lane >> 4, c = lane & 15;

    if (tid < QB * 3) xs[tid] = x_q[q0 * 3 + tid];
    __syncthreads();
    if (tid < EB) {
        int e = tid, q = e >> 4;
        int gi = erow[q0 * DEG + e] - N_PTS;
        sgi[e] = gi;
        int gl = gi & (GPTS - 1);
        float r0 = gridp[gl * 3 + 0] - xs[q * 3 + 0];
        float r1 = gridp[gl * 3 + 1] - xs[q * 3 + 1];
        float r2 = gridp[gl * 3 + 2] - xs[q * 3 + 2];
        float dist = sqrtf(r0 * r0 + r1 * r1 + r2 * r2);
        float inv = 1.0f / (dist + 1e-8f);
        sdist[e] = dist;
        sdir[0 * EB + e] = r0 * inv;
        sdir[1 * EB + e] = r1 * inv;
        sdir[2 * EB + e] = r2 * inv;
        float cw = 0.5f * (__cosf(dist * 0.31415926535897931f) + 1.0f);
        scm[e] = (dist <= 10.0f) ? cw : 0.0f;
    }
    __syncthreads();

    int gi_[2]; float dist_[2];
#pragma unroll
    for (int mi = 0; mi < 2; mi++) {
        int e = (wid * 2 + mi) * 16 + c;
        gi_[mi] = sgi[e];
        dist_[mi] = sdist[e];
    }

    floatx4 acc[2][8];
#pragma unroll
    for (int mi = 0; mi < 2; mi++)
#pragma unroll
        for (int n = 0; n < 8; n++) acc[mi][n] = (floatx4)0.f;

    // Ag software pipeline: chunk 0 preload, then prefetch ch+1 under compute of ch
    float4 pA0[2], pA1[2], nA0[2], nA1[2];
#pragma unroll
    for (int mi = 0; mi < 2; mi++) {
        const float4* ap = (const float4*)(Ag + gi_[mi] * HD + quad * 8);
        pA0[mi] = ap[0]; pA1[mi] = ap[1];
    }
#pragma unroll
    for (int ch = 0; ch < 4; ch++) {
        int kb = ch * 32 + quad * 8;
        if (ch < 3) {
#pragma unroll
            for (int mi = 0; mi < 2; mi++) {
                const float4* ap = (const float4*)(Ag + gi_[mi] * HD + (ch + 1) * 32 + quad * 8);
                nA0[mi] = ap[0]; nA1[mi] = ap[1];
            }
        }
        float4 wd0 = *(const float4*)(wdrow + kb);
        float4 wd1 = *(const float4*)(wdrow + kb + 4);
        short8 afr[2];
#pragma unroll
        for (int mi = 0; mi < 2; mi++) {
            int q = wid * 2 + mi;
            float dist = dist_[mi];
            const float4* bp4 = (const float4*)(Bq + (q0 + q) * HD + kb);
            float4 b0 = bp4[0], b1 = bp4[1];
            float4 a0 = pA0[mi], a1 = pA1[mi];
            short8 v;
            v[0] = f2bf(silu_f(a0.x + b0.x + dist * wd0.x));
            v[1] = f2bf(silu_f(a0.y + b0.y + dist * wd0.y));
            v[2] = f2bf(silu_f(a0.z + b0.z + dist * wd0.z));
            v[3] = f2bf(silu_f(a0.w + b0.w + dist * wd0.w));
            v[4] = f2bf(silu_f(a1.x + b1.x + dist * wd1.x));
            v[5] = f2bf(silu_f(a1.y + b1.y + dist * wd1.y));
            v[6] = f2bf(silu_f(a1.z + b1.z + dist * wd1.z));
            v[7] = f2bf(silu_f(a1.w + b1.w + dist * wd1.w));
            afr[mi] = v;
        }
#pragma unroll
        for (int n = 0; n < 8; n++) {
            short8 bfr = *(const short8*)(wsT + (n * 16 + c) * HD + kb);
            acc[0][n] = __builtin_amdgcn_mfma_f32_16x16x32_bf16(afr[0], bfr, acc[0][n], 0, 0, 0);
            acc[1][n] = __builtin_amdgcn_mfma_f32_16x16x32_bf16(afr[1], bfr, acc[1][n], 0, 0, 0);
        }
#pragma unroll
        for (int mi = 0; mi < 2; mi++) { pA0[mi] = nA0[mi]; pA1[mi] = nA1[mi]; }
    }

#pragma unroll
    for (int mi = 0; mi < 2; mi++) {
        int q = wid * 2 + mi;
        int ebase = q * 16;
        float cmr[4];
#pragma unroll
        for (int r = 0; r < 4; r++) cmr[r] = scm[ebase + quad * 4 + r];
        float apc[4][OUTT];
#pragma unroll
        for (int r = 0; r < 4; r++)
#pragma unroll
            for (int t = 0; t < OUTT; t++) apc[r][t] = 0.f;
#pragma unroll
        for (int n = 0; n < 8; n++) {
            int f = n * 16 + c;
            float be2v = b2v[f];
            float wcv[OUTT];
            if (FIN) {
#pragma unroll
                for (int t = 0; t < OUTT; t++) wcv[t] = Wc[f * 5 + t];
            } else {
                wcv[0] = Wc[f];
            }
            float cs = 0.f;
#pragma unroll
            for (int r = 0; r < 4; r++) {
                float v = silu_f(acc[mi][n][r] + be2v) * cmr[r];
                cs += v;
#pragma unroll
                for (int t = 0; t < OUTT; t++) apc[r][t] += v * wcv[t];
            }
            cs += __shfl_xor(cs, 16, 64);
            cs += __shfl_xor(cs, 32, 64);
            if (!FIN && lane < 16) maggr[(q0 + q) * HD + f] = cs * 0.0625f;
        }
#pragma unroll
        for (int t = 0; t < OUTT; t++) {
#pragma unroll
            for (int r = 0; r < 4; r++) {
                float v = apc[r][t];
                v += __shfl_xor(v, 1, 64);
                v += __shfl_xor(v, 2, 64);
                v += __shfl_xor(v, 4, 64);
                v += __shfl_xor(v, 8, 64);
                if (c == 0) scoef[(ebase + quad * 4 + r) * OUTT + t] = v;
            }
        }
    }
    __syncthreads();

    if (tid < QB * 3 * OUTT) {
        int qq = tid / (3 * OUTT), rem = tid % (3 * OUTT), t = rem / 3, c2 = rem % 3;
        float cbv = cbp[t];
        float s = 0.f;
#pragma unroll 4
        for (int r = 0; r < 16; r++) {
            int ee = qq * 16 + r;
            s += (scoef[ee * OUTT + t] + cbv) * sdir[c2 * EB + ee];
        }
        float dd = s * 0.0625f;
        if (FIN) out[(q0 + qq) * 15 + t * 3 + c2] = xs[qq * 3 + c2] + dd - qp[(q0 + qq) * 3 + c2];
        else x_q[(q0 + qq) * 3 + c2] = xs[qq * 3 + c2] + dd;
    }
}

extern "C" void kernel_launch(void* const* d_in, const int* in_sizes, int n_in,
                              void* d_out, int out_size, void* d_ws, size_t ws_size,
                              hipStream_t stream) {
    float* out = (float*)d_out;
    int fill_blocks = (out_size + 255) / 256;

    static const int exp_sz[16] = { 49152, 524288, 1536, 131584, 512, 65536, 512, 384,
                                    3, 640, 5, 131072, 512, 65536, 512, 524288 };
    bool ok = (n_in == 16);
    for (int i = 0; ok && i < 16; i++) if (in_sizes[i] != exp_sz[i]) ok = false;
    if (!ok || ws_size < (size_t)40 * 1024 * 1024) {
        k_fillf<<<fill_blocks, 256, 0, stream>>>(out, 777.0f, out_size);
        return;
    }

    const float* qp    = (const float*)d_in[0];
    const float* codes = (const float*)d_in[1];
    const float* gridp = (const float*)d_in[2];
    const float* eW1   = (const float*)d_in[3];
    const float* eb1   = (const float*)d_in[4];
    const float* eW2   = (const float*)d_in[5];
    const float* eb2   = (const float*)d_in[6];
    const float* cW    = (const float*)d_in[7];
    const float* cb    = (const float*)d_in[8];
    const float* fcW   = (const float*)d_in[9];
    const float* fcb   = (const float*)d_in[10];
    const float* nW1   = (const float*)d_in[11];
    const float* nb1   = (const float*)d_in[12];
    const float* nW2   = (const float*)d_in[13];
    const float* nb2   = (const float*)d_in[14];
    const int*   erow  = (const int*)d_in[15];

    float* ws = (float*)d_ws;
    float* x_q  = ws;  ws += N_PTS * 3;
    float* h_q  = ws;  ws += N_PTS * HD;
    float* hg_a = ws;  ws += N_GRID * HD;
    float* hg_b = ws;  ws += N_GRID * HD;
    float* A_g  = ws;  ws += N_GRID * HD;
    float* Bqb  = ws;  ws += N_PTS * HD;
    float* mgb  = ws;  ws += N_PTS * HD;
    short* wsT  = (short*)ws;   // 4 layers x 16384 bf16

    k_init<<<2048, 256, 0, stream>>>(qp, codes, x_q, hg_a, h_q);
    k_prep<<<(4 * HD * HD + 255) / 256, 256, 0, stream>>>(eW2, wsT);

    float* hg_cur = hg_a;
    float* hg_next = hg_b;
    for (int i = 0; i < 4; i++) {
        int fin = (i == 3);
        const float* W1l = eW1 + i * 257 * 128;
        k_gb<<<N_GRID / 32 + N_PTS / 32, 256, 0, stream>>>(
            hg_cur, A_g, W1l, eb1 + i * 128,
            nW1 + i * 256 * 128, nb1 + i * 128, nW2 + i * 16384, nb2 + i * 128,
            fin ? 0 : 1, hg_next, h_q, W1l + 128 * 128, Bqb);
        if (!fin) {
            k_edge<1, false><<<N_PTS / QB, 256, 0, stream>>>(A_g, Bqb, x_q,
                W1l + 256 * 128, wsT + i * 16384, eb2 + i * 128,
                cW + i * 128, cb + i, erow, gridp, qp, out, mgb);
            k_node<<<N_PTS / 32, 256, 0, stream>>>(h_q, mgb, nW1 + i * 256 * 128,
                nb1 + i * 128, nW2 + i * 16384, nb2 + i * 128);
        } else {
            k_edge<5, true><<<N_PTS / QB, 256, 0, stream>>>(A_g, Bqb, x_q,
                W1l + 256 * 128, wsT + i * 16384, eb2 + i * 128,
                fcW, fcb, erow, gridp, qp, out, mgb);
        }
        float* tmp = hg_cur; hg_cur = hg_next; hg_next = tmp;
    }
}